// Round 9
// baseline (19153.680 us; speedup 1.0000x reference)
//
#include <hip/hip_runtime.h>
#include <stdint.h>

#define N_B 32
#define T_S 2048
#define H_D 1024
#define NGRP 8                         // groups; 32 blocks each, 4 batches each
// workspace layout: f32 data [2][NGRP][1024][4] = 256 KB, then counters
#define CNT_BYTE_OFF (256 * 1024)

typedef unsigned long long u64;

// One DPP f32 add-reduce step: x += dpp(x) on enabled rows.
template<int CTRL, int ROWMASK>
__device__ __forceinline__ float dpp_add(float x) {
    int t = __builtin_amdgcn_update_dpp(0, __builtin_bit_cast(int, x),
                                        CTRL, ROWMASK, 0xf, true);
    return x + __builtin_bit_cast(float, t);
}

// fast tanh: clamp + v_exp_f32 + v_rcp_f32;  |err| ~1e-6, threshold 1.3e-2
__device__ __forceinline__ float fast_tanh(float x) {
    float xc = fminf(fmaxf(x, -10.0f), 10.0f);
    float e  = __builtin_amdgcn_exp2f(xc * 2.885390081777927f);  // e^{2x}
    return (e - 1.0f) * __builtin_amdgcn_rcpf(e + 1.0f);
}

// Persistent RNN kernel — W in LDS col-major (r8, conflict-free, proven);
// NEW: counter-based group sync replaces per-packet tag polling.
//
// Per step, per group of 32 blocks:
//   producers: store 128 plain f32 (relaxed atomic, agent) -> __syncthreads
//   (drains vmcnt) -> thread0: fetch_add(counter, 1, RELEASE).
//   consumers: thread0 polls counter >= 32*(t-1) (acquire) -> __syncthreads ->
//   every thread issues its 4 u64 data loads ONCE (no data spinning).
// Counter is cumulative (monotone): counter >= 32t iff ALL 32 blocks
// published step t — a block can only add for t+1 after seeing >= 32t.
// Parity double-buffer keeps writes one full step behind reads. memset per
// call (inside the captured graph) resets counters -> no cross-replay ABA.
__global__ __launch_bounds__(512, 1) void rnn_persist(
    const int* __restrict__ xx, const float* __restrict__ embed,
    const float* __restrict__ W, const float* __restrict__ bh,
    float* __restrict__ out, u64* __restrict__ ws)
{
    __shared__ float  wlds[32 * 1024];   // W slice, col-major, 128 KB
    __shared__ float2 h2[2][1024];       // h planes: [pair][row], 16 KB
    __shared__ float  xh_lds[4][32];     // embed slice for current step

    float*    hdat = (float*)ws;                                   // [2][8][1024][4]
    unsigned* cnt  = (unsigned*)((char*)ws + CNT_BYTE_OFF);        // stride 64 u32

    const int tid = threadIdx.x;
    const int blk = blockIdx.x;
    const int g  = blk & 7;            // group (32 blocks, XCD-local heuristic)
    const int s  = blk >> 3;           // col slice 0..31
    const int n0 = g * 4;
    const int wv = tid >> 6;           // wave id: col chunk (4 cols)
    const int rc = tid & 63;           // lane: row chunk
    const int c_base = s * 32 + wv * 4;
    unsigned* cnt_g = cnt + g * 64;    // 256B apart -> no false sharing

    // ---- one-time: stage W slice into LDS, col-major ----
    {
        int r0 = tid >> 3, c4 = tid & 7;   // 8 threads per row, 4 cols each
        for (int i = 0; i < 16; ++i) {
            int row = r0 + i * 64;
            float4 v = *(const float4*)(W + (size_t)row * H_D + s * 32 + c4 * 4);
            wlds[(c4 * 4 + 0) * 1024 + row] = v.x;
            wlds[(c4 * 4 + 1) * 1024 + row] = v.y;
            wlds[(c4 * 4 + 2) * 1024 + row] = v.z;
            wlds[(c4 * 4 + 3) * 1024 + row] = v.w;
        }
    }
    for (int e = tid; e < 1024; e += 512) {
        h2[0][e] = float2{0.0f, 0.0f};     // h_0 = 0
        h2[1][e] = float2{0.0f, 0.0f};
    }
    __syncthreads();

    // lanes 48..63 of each wave own its 16 outputs (4 batches x 4 cols)
    const int o  = rc - 48;
    const int ob = (o >> 2) & 3, oj = o & 3;
    int my_n = 0, my_c = 0, xh_i = 0; float my_bias = 0.0f;
    if (o >= 0) {
        my_c    = c_base + oj;
        my_n    = n0 + ob;
        my_bias = bh[my_c];
        xh_i    = ob * 32 + (wv * 4 + oj);
    }

    // ---- embed prefetch chain ----
    float r_xh = 0.0f;   // embed value for the CURRENT step
    int   r_tok = 0;     // token for the NEXT step
    const int eb = tid >> 5, ec = tid & 31;      // batch, col (tid < 128)
    if (tid < 128) {
        int tok0 = xx[(size_t)(n0 + eb) * T_S + 0];
        r_xh  = embed[(size_t)tok0 * H_D + s * 32 + ec];
        r_tok = xx[(size_t)(n0 + eb) * T_S + 1];
    }

    // per-wave bases for the GEMV (all inner offsets are compile-time imms)
    const float*  wbase = &wlds[(wv * 4) * 1024 + rc];
    const float2* hb0   = &h2[0][rc];
    const float2* hb1   = &h2[1][rc];

    for (int t = 1; t <= T_S; ++t) {
        // 1. stage xh for this step; issue prefetch for next (overlaps poll)
        if (tid < 128) {
            xh_lds[eb][ec] = r_xh;
            int tok = r_tok;
            int ti  = t + 1 < T_S ? t + 1 : T_S - 1;
            r_tok = xx[(size_t)(n0 + eb) * T_S + ti];
            r_xh  = embed[(size_t)tok * H_D + s * 32 + ec];
        }
        // 2. wait for h_{t-1}: ONE poller per block on ONE counter line
        if (t >= 2) {
            if (tid == 0) {
                const unsigned tgt = 32u * (unsigned)(t - 1);
                while (__hip_atomic_load(cnt_g, __ATOMIC_RELAXED,
                                         __HIP_MEMORY_SCOPE_AGENT) < tgt) {}
                (void)__hip_atomic_load(cnt_g, __ATOMIC_ACQUIRE,
                                        __HIP_MEMORY_SCOPE_AGENT);
            }
            __syncthreads();   // B1: releases block; acquire sync propagates
            // bulk-load h data ONCE (u64 pairs {b0,b1},{b2,b3}); stage to LDS
            const size_t base64 = ((size_t)(((t - 1) & 1) * NGRP + g)) * 1024 * 2;
            u64* hq = (u64*)hdat;
            u64 q0 = __hip_atomic_load(&hq[base64 + (size_t)tid * 2],
                                       __ATOMIC_RELAXED, __HIP_MEMORY_SCOPE_AGENT);
            u64 q1 = __hip_atomic_load(&hq[base64 + (size_t)tid * 2 + 1],
                                       __ATOMIC_RELAXED, __HIP_MEMORY_SCOPE_AGENT);
            u64 q2 = __hip_atomic_load(&hq[base64 + (size_t)(tid + 512) * 2],
                                       __ATOMIC_RELAXED, __HIP_MEMORY_SCOPE_AGENT);
            u64 q3 = __hip_atomic_load(&hq[base64 + (size_t)(tid + 512) * 2 + 1],
                                       __ATOMIC_RELAXED, __HIP_MEMORY_SCOPE_AGENT);
            h2[0][tid]       = __builtin_bit_cast(float2, q0);
            h2[1][tid]       = __builtin_bit_cast(float2, q1);
            h2[0][tid + 512] = __builtin_bit_cast(float2, q2);
            h2[1][tid + 512] = __builtin_bit_cast(float2, q3);
        }
        __syncthreads();   // B2: h2 + xh_lds visible to all

        // 3. partial GEMV: 16 rows x 4 cols x 4 batches; W streamed from LDS
        //    (b32, bank = rc%32, exactly 2 lanes/bank = free)
        float acc[4][4];
#pragma unroll
        for (int b = 0; b < 4; ++b)
#pragma unroll
            for (int j = 0; j < 4; ++j) acc[b][j] = 0.0f;
#pragma unroll
        for (int k = 0; k < 16; ++k) {
            float2 a01 = hb0[k * 64];
            float2 a23 = hb1[k * 64];
            float w0 = wbase[k * 64];
            float w1 = wbase[k * 64 + 1024];
            float w2 = wbase[k * 64 + 2048];
            float w3 = wbase[k * 64 + 3072];
            acc[0][0] = fmaf(a01.x, w0, acc[0][0]);
            acc[0][1] = fmaf(a01.x, w1, acc[0][1]);
            acc[0][2] = fmaf(a01.x, w2, acc[0][2]);
            acc[0][3] = fmaf(a01.x, w3, acc[0][3]);
            acc[1][0] = fmaf(a01.y, w0, acc[1][0]);
            acc[1][1] = fmaf(a01.y, w1, acc[1][1]);
            acc[1][2] = fmaf(a01.y, w2, acc[1][2]);
            acc[1][3] = fmaf(a01.y, w3, acc[1][3]);
            acc[2][0] = fmaf(a23.x, w0, acc[2][0]);
            acc[2][1] = fmaf(a23.x, w1, acc[2][1]);
            acc[2][2] = fmaf(a23.x, w2, acc[2][2]);
            acc[2][3] = fmaf(a23.x, w3, acc[2][3]);
            acc[3][0] = fmaf(a23.y, w0, acc[3][0]);
            acc[3][1] = fmaf(a23.y, w1, acc[3][1]);
            acc[3][2] = fmaf(a23.y, w2, acc[3][2]);
            acc[3][3] = fmaf(a23.y, w3, acc[3][3]);
        }

        // 4. 64-lane reduce of 16 values; totals land in lanes 48..63
        float outv = 0.0f;
#pragma unroll
        for (int oo = 0; oo < 16; ++oo) {
            float v = acc[oo >> 2][oo & 3];
            v = dpp_add<0xB1,  0xf>(v);   // quad_perm xor1
            v = dpp_add<0x4E,  0xf>(v);   // quad_perm xor2
            v = dpp_add<0x141, 0xf>(v);   // row_half_mirror -> sum of 8
            v = dpp_add<0x140, 0xf>(v);   // row_mirror      -> sum of 16
            v = dpp_add<0x142, 0xa>(v);   // row_bcast15 -> rows 1,3
            v = dpp_add<0x143, 0xc>(v);   // row_bcast31 -> row 3 = total
            if (o == oo) outv = v;
        }

        // 5. epilogue: tanh, publish data (plain f32, relaxed atomic), z-write
        if (o >= 0) {
            float pre = outv + ((const float*)xh_lds)[xh_i] + my_bias;
            float hv  = fast_tanh(pre);
            hdat[((size_t)((t & 1) * NGRP + g) * 1024 + my_c) * 4 + ob] = hv;
            // ^ plain store is ordered by the RELEASE add below (after barrier
            //   drain); consumers read via coherence-point atomic loads.
            out[((size_t)my_n * T_S + (t - 1)) * H_D + my_c] = hv;
            if (t == T_S)
                out[(size_t)N_B * T_S * H_D + (size_t)my_n * H_D + my_c] = hv;
        }
        __syncthreads();   // B3: drains vmcnt(0) -> all data stores complete
        if (tid == 0)
            __hip_atomic_fetch_add(cnt_g, 1u, __ATOMIC_RELEASE,
                                   __HIP_MEMORY_SCOPE_AGENT);
    }
}

extern "C" void kernel_launch(void* const* d_in, const int* in_sizes, int n_in,
                              void* d_out, int out_size, void* d_ws, size_t ws_size,
                              hipStream_t stream) {
    const int*   xx    = (const int*)d_in[0];
    const float* embed = (const float*)d_in[1];
    const float* W     = (const float*)d_in[2];
    const float* bh    = (const float*)d_in[3];
    float* out = (float*)d_out;
    u64*   ws  = (u64*)d_ws;

    // zero data + counters each call (captured in graph -> runs every replay)
    hipMemsetAsync(d_ws, 0, CNT_BYTE_OFF + NGRP * 256, stream);

    void* args[] = { (void*)&xx, (void*)&embed, (void*)&W, (void*)&bh,
                     (void*)&out, (void*)&ws };
    hipLaunchCooperativeKernel((const void*)rnn_persist, dim3(256), dim3(512),
                               args, 0, stream);
}

// Round 10
// 7172.281 us; speedup vs baseline: 2.6705x; 2.6705x over previous
//
#include <hip/hip_runtime.h>
#include <stdint.h>

#define N_B 32
#define T_S 2048
#define H_D 1024
#define NSET 8                       // 8 sets x 32 blocks; set owns 4 batches

typedef unsigned long long u64;

// One DPP f32 add-reduce step: x += dpp(x) on enabled rows.
template<int CTRL, int ROWMASK>
__device__ __forceinline__ float dpp_add(float x) {
    int t = __builtin_amdgcn_update_dpp(0, __builtin_bit_cast(int, x),
                                        CTRL, ROWMASK, 0xf, true);
    return x + __builtin_bit_cast(float, t);
}

// Spin until packet tag matches `want` (tagged data: the load IS the poll,
// so data latency self-hides). Periodic RMW = livelock insurance only.
__device__ __forceinline__ u64 wait_pkt(u64* a, unsigned want, u64 v) {
    int spins = 0;
    while ((unsigned)(v >> 32) != want) {
        if ((++spins & 63) == 0)
            v = __hip_atomic_fetch_or(a, 0ull, __ATOMIC_RELAXED, __HIP_MEMORY_SCOPE_AGENT);
        else
            v = __hip_atomic_load(a, __ATOMIC_RELAXED, __HIP_MEMORY_SCOPE_AGENT);
    }
    return v;
}

// fast tanh: clamp + v_exp_f32 + v_rcp_f32;  |err| ~1e-6, threshold 1.3e-2
__device__ __forceinline__ float fast_tanh(float x) {
    float xc = fminf(fmaxf(x, -10.0f), 10.0f);
    float e  = __builtin_amdgcn_exp2f(xc * 2.885390081777927f);  // e^{2x}
    return (e - 1.0f) * __builtin_amdgcn_rcpf(e + 1.0f);
}

// Persistent RNN — W in LDS col-major (r8 layout: bank = rc%32, 2 lanes/bank,
// free). NEW vs r8: the set's 4 batches split into TWO chains interleaved in
// time, so each chain's publish->poll MALL round-trip hides behind the OTHER
// chain's compute. No RMW on the hot path (r9 lesson: shared-line fetch_add
// serializes ~32x at the coherence point).
//
// Per t:  P1 compute+publish chain A | P2 compute+publish chain B | BAR1 |
//         P3 poll A -> LDS | P4 poll B -> LDS | xh stage | BAR2.
// Packets: u64 (tag<<32 | f32 bits), parity double-buffered; overwrite of
// slot (p,t) happens at t+2, only after every block consumed tag t (same
// induction as r2). memset per call kills cross-replay stale tags.
__global__ __launch_bounds__(512, 1) void rnn_persist(
    const int* __restrict__ xx, const float* __restrict__ embed,
    const float* __restrict__ W, const float* __restrict__ bh,
    float* __restrict__ out, u64* __restrict__ ws)
{
    __shared__ float  wlds[32 * 1024];   // W slice, col-major, 128 KB
    __shared__ float2 h2A[1024];         // chain A h: {b0,b1} per row
    __shared__ float2 h2B[1024];         // chain B h: {b2,b3} per row
    __shared__ float  xhA[2][32];        // embed slice, chain A, current step
    __shared__ float  xhB[2][32];

    const int tid = threadIdx.x;
    const int blk = blockIdx.x;
    const int g  = blk & 7;              // set id
    const int s  = blk >> 3;             // col slice 0..31
    const int n0 = g * 4;                // set's first batch
    const int wv = tid >> 6;             // wave id: 4-col chunk
    const int rc = tid & 63;             // lane
    const int c_base = s * 32 + wv * 4;

    // ---- one-time: stage W slice into LDS, col-major (proven r8) ----
    {
        int r0 = tid >> 3, c4 = tid & 7;
        for (int i = 0; i < 16; ++i) {
            int row = r0 + i * 64;
            float4 v = *(const float4*)(W + (size_t)row * H_D + s * 32 + c4 * 4);
            wlds[(c4 * 4 + 0) * 1024 + row] = v.x;
            wlds[(c4 * 4 + 1) * 1024 + row] = v.y;
            wlds[(c4 * 4 + 2) * 1024 + row] = v.z;
            wlds[(c4 * 4 + 3) * 1024 + row] = v.w;
        }
    }
    for (int e = tid; e < 1024; e += 512) {
        h2A[e] = float2{0.0f, 0.0f};     // h_0 = 0
        h2B[e] = float2{0.0f, 0.0f};
    }

    // ---- embed pre-stage: xh for step 1 direct; prefetch step 2 ----
    const int eb = tid >> 5, ec = tid & 31;   // batch-in-set, col (tid<128)
    float r_xh = 0.0f;   // embed value for step t+1 (at staging time)
    int   r_tok = 0;     // token x[t+1] (at staging time)
    if (tid < 128) {
        const size_t nn = (size_t)(n0 + eb) * T_S;
        int tk0 = xx[nn + 0];
        float v0 = embed[(size_t)tk0 * H_D + s * 32 + ec];
        if (eb < 2) xhA[eb][ec] = v0; else xhB[eb - 2][ec] = v0;
        int tk1 = xx[nn + 1];
        r_xh  = embed[(size_t)tk1 * H_D + s * 32 + ec];
        r_tok = xx[nn + 2];
    }
    __syncthreads();

    // lanes 56..63 of each wave own its 8 outputs (2 batches x 4 cols) per chain
    const int o = rc - 56;
    int my_c = 0, xh_i = 0; float biasv = 0.0f;
    if (o >= 0) {
        const int oj = o & 3;
        my_c  = c_base + oj;
        biasv = bh[my_c];
        xh_i  = ((o >> 2) & 1) * 32 + (wv * 4 + oj);
    }
    const int ob = (o >= 0) ? ((o >> 2) & 1) : 0;

    const float* wbase = &wlds[(wv * 4) * 1024 + rc];
    // packet indexing: [parity][set][chain][batch-in-chain][row]
#define PKT(P, CH, B, ROW) (ws + ((((size_t)(P) * NSET + g) * 2 + (CH)) * 2 + (B)) * 1024 + (ROW))

    for (int t = 1; t <= T_S; ++t) {
        const int p = t & 1;

        // ================= P1 + P2: compute & publish both chains ==========
#pragma unroll
        for (int ch = 0; ch < 2; ++ch) {
            const float2* hb = ch ? &h2B[rc] : &h2A[rc];
            float acc[2][4];
#pragma unroll
            for (int b = 0; b < 2; ++b)
#pragma unroll
                for (int j = 0; j < 4; ++j) acc[b][j] = 0.0f;
#pragma unroll
            for (int k = 0; k < 16; ++k) {
                float2 a  = hb[k * 64];
                float w0 = wbase[k * 64];
                float w1 = wbase[k * 64 + 1024];
                float w2 = wbase[k * 64 + 2048];
                float w3 = wbase[k * 64 + 3072];
                acc[0][0] = fmaf(a.x, w0, acc[0][0]);
                acc[0][1] = fmaf(a.x, w1, acc[0][1]);
                acc[0][2] = fmaf(a.x, w2, acc[0][2]);
                acc[0][3] = fmaf(a.x, w3, acc[0][3]);
                acc[1][0] = fmaf(a.y, w0, acc[1][0]);
                acc[1][1] = fmaf(a.y, w1, acc[1][1]);
                acc[1][2] = fmaf(a.y, w2, acc[1][2]);
                acc[1][3] = fmaf(a.y, w3, acc[1][3]);
            }
            // 64-lane reduce of 8 values; totals land in lanes 48..63 (row 3)
            float outv = 0.0f;
#pragma unroll
            for (int oo = 0; oo < 8; ++oo) {
                float v = acc[oo >> 2][oo & 3];
                v = dpp_add<0xB1,  0xf>(v);   // quad_perm xor1
                v = dpp_add<0x4E,  0xf>(v);   // quad_perm xor2
                v = dpp_add<0x141, 0xf>(v);   // row_half_mirror -> sum of 8
                v = dpp_add<0x140, 0xf>(v);   // row_mirror      -> sum of 16
                v = dpp_add<0x142, 0xa>(v);   // row_bcast15 -> rows 1,3
                v = dpp_add<0x143, 0xc>(v);   // row_bcast31 -> row 3 = total
                if (o == oo) outv = v;
            }
            if (o >= 0) {
                const float* xh = ch ? (const float*)xhB : (const float*)xhA;
                float pre = outv + xh[xh_i] + biasv;
                float hv  = fast_tanh(pre);
                // publish FIRST (consumer-visible store leads the chain)
                u64 pk = ((u64)(unsigned)t << 32)
                       | (u64)__builtin_bit_cast(unsigned, hv);
                __hip_atomic_store(PKT(p, ch, ob, my_c), pk,
                                   __ATOMIC_RELAXED, __HIP_MEMORY_SCOPE_AGENT);
                const int n = n0 + ch * 2 + ob;
                out[((size_t)n * T_S + (t - 1)) * H_D + my_c] = hv;
                if (t == T_S)
                    out[(size_t)N_B * T_S * H_D + (size_t)n * H_D + my_c] = hv;
            }
        }
        __syncthreads();   // BAR1: all GEMV/xh reads of step t complete

        // ============ P3 + P4: fetch h_t (tag=t) for step t+1 ==============
        if (t < T_S) {
            const unsigned tag = (unsigned)t;
            u64 *aA0 = PKT(p, 0, 0, tid),       *aA1 = PKT(p, 0, 1, tid);
            u64 *aA2 = PKT(p, 0, 0, tid + 512), *aA3 = PKT(p, 0, 1, tid + 512);
            u64 *aB0 = PKT(p, 1, 0, tid),       *aB1 = PKT(p, 1, 1, tid);
            u64 *aB2 = PKT(p, 1, 0, tid + 512), *aB3 = PKT(p, 1, 1, tid + 512);
            // issue all 8 loads up front (pipelined MALL latency)
            u64 vA0 = __hip_atomic_load(aA0, __ATOMIC_RELAXED, __HIP_MEMORY_SCOPE_AGENT);
            u64 vA1 = __hip_atomic_load(aA1, __ATOMIC_RELAXED, __HIP_MEMORY_SCOPE_AGENT);
            u64 vA2 = __hip_atomic_load(aA2, __ATOMIC_RELAXED, __HIP_MEMORY_SCOPE_AGENT);
            u64 vA3 = __hip_atomic_load(aA3, __ATOMIC_RELAXED, __HIP_MEMORY_SCOPE_AGENT);
            u64 vB0 = __hip_atomic_load(aB0, __ATOMIC_RELAXED, __HIP_MEMORY_SCOPE_AGENT);
            u64 vB1 = __hip_atomic_load(aB1, __ATOMIC_RELAXED, __HIP_MEMORY_SCOPE_AGENT);
            u64 vB2 = __hip_atomic_load(aB2, __ATOMIC_RELAXED, __HIP_MEMORY_SCOPE_AGENT);
            u64 vB3 = __hip_atomic_load(aB3, __ATOMIC_RELAXED, __HIP_MEMORY_SCOPE_AGENT);

            // xh staging for step t+1 (overlaps the packet waits)
            if (tid < 128) {
                if (eb < 2) xhA[eb][ec] = r_xh; else xhB[eb - 2][ec] = r_xh;
                int ti = t + 2 < T_S ? t + 2 : T_S - 1;
                r_xh  = embed[(size_t)r_tok * H_D + s * 32 + ec];
                r_tok = xx[(size_t)(n0 + eb) * T_S + ti];
            }

            vA0 = wait_pkt(aA0, tag, vA0);
            vA1 = wait_pkt(aA1, tag, vA1);
            vA2 = wait_pkt(aA2, tag, vA2);
            vA3 = wait_pkt(aA3, tag, vA3);
            h2A[tid]       = float2{ __builtin_bit_cast(float, (unsigned)vA0),
                                     __builtin_bit_cast(float, (unsigned)vA1) };
            h2A[tid + 512] = float2{ __builtin_bit_cast(float, (unsigned)vA2),
                                     __builtin_bit_cast(float, (unsigned)vA3) };
            vB0 = wait_pkt(aB0, tag, vB0);
            vB1 = wait_pkt(aB1, tag, vB1);
            vB2 = wait_pkt(aB2, tag, vB2);
            vB3 = wait_pkt(aB3, tag, vB3);
            h2B[tid]       = float2{ __builtin_bit_cast(float, (unsigned)vB0),
                                     __builtin_bit_cast(float, (unsigned)vB1) };
            h2B[tid + 512] = float2{ __builtin_bit_cast(float, (unsigned)vB2),
                                     __builtin_bit_cast(float, (unsigned)vB3) };
        }
        __syncthreads();   // BAR2: new h/xh visible before next step
    }
#undef PKT
}

extern "C" void kernel_launch(void* const* d_in, const int* in_sizes, int n_in,
                              void* d_out, int out_size, void* d_ws, size_t ws_size,
                              hipStream_t stream) {
    const int*   xx    = (const int*)d_in[0];
    const float* embed = (const float*)d_in[1];
    const float* W     = (const float*)d_in[2];
    const float* bh    = (const float*)d_in[3];
    float* out = (float*)d_out;
    u64*   ws  = (u64*)d_ws;

    // clear all packet tags each call (2*8*2*2*1024 u64 = 512 KB)
    hipMemsetAsync(d_ws, 0, (size_t)2 * NSET * 2 * 2 * 1024 * sizeof(u64), stream);

    void* args[] = { (void*)&xx, (void*)&embed, (void*)&W, (void*)&bh,
                     (void*)&out, (void*)&ws };
    hipLaunchCooperativeKernel((const void*)rnn_persist, dim3(256), dim3(512),
                               args, 0, stream);
}